// Round 5
// baseline (101.301 us; speedup 1.0000x reference)
//
#include <hip/hip_runtime.h>

static constexpr int B_ = 64;
static constexpr int L_ = 1 << 20;
static constexpr int OUT_LEN = 2 * (L_ >> 2) - 1; // 524287

__device__ __forceinline__ float dot4(const float4& v, float t0, float t1, float t2, float t3) {
    return fmaf(v.x, t0, fmaf(v.y, t1, fmaf(v.z, t2, v.w * t3)));
}

// v += dpp(v) on the VALU pipe. old=0 so masked-off rows contribute +0.
template<int CTRL, int RM>
__device__ __forceinline__ float dpp_add(float v) {
    int t = __builtin_amdgcn_update_dpp(0, __builtin_bit_cast(int, v), CTRL, RM, 0xF, true);
    return v + __builtin_bit_cast(float, t);
}

// Segmented sum over groups of M consecutive lanes; result in LAST lane of group.
template<int M>
__device__ __forceinline__ float seg_reduce(float v) {
    if constexpr (M >= 2)  v = dpp_add<0x111, 0xF>(v);  // row_shr:1
    if constexpr (M >= 4)  v = dpp_add<0x112, 0xF>(v);  // row_shr:2
    if constexpr (M >= 8)  v = dpp_add<0x114, 0xF>(v);  // row_shr:4
    if constexpr (M >= 16) v = dpp_add<0x118, 0xF>(v);  // row_shr:8
    if constexpr (M >= 32) v = dpp_add<0x142, 0xA>(v);  // row_bcast15
    if constexpr (M >= 64) v = dpp_add<0x143, 0xC>(v);  // row_bcast31
    return v;
}

template<int S>
__device__ __forceinline__ void scale_compute(const float4& v0, const float4& v1,
                                              const float4& v2, const float4& v3,
                                              const float4& tp, float bs,
                                              float* __restrict__ orow, int c, int lane) {
    constexpr int m = (1 << S) >> 2;
    float p0 = seg_reduce<m>(dot4(v0, tp.x, tp.y, tp.z, tp.w));
    float p1 = seg_reduce<m>(dot4(v1, tp.x, tp.y, tp.z, tp.w));
    float p2 = seg_reduce<m>(dot4(v2, tp.x, tp.y, tp.z, tp.w));
    float p3 = seg_reduce<m>(dot4(v3, tp.x, tp.y, tp.z, tp.w));
    if ((lane & (m - 1)) == (m - 1)) {
        constexpr int base = (L_ >> S) - 1;
        constexpr int sps  = 256 >> S;
        const int seg = c * (1024 >> S) + (lane >> (S - 2));
        orow[base + seg          ] = p0 + bs;
        orow[base + seg +     sps] = p1 + bs;
        orow[base + seg + 2 * sps] = p2 + bs;
        orow[base + seg + 3 * sps] = p3 + bs;
    }
}

__global__ __launch_bounds__(256, 4) void multiscale_conv(
    const float* __restrict__ data,
    const float* __restrict__ weights,
    const float* __restrict__ bias,
    float* __restrict__ out)
{
    const int lane = threadIdx.x & 63;
    const int wv   = threadIdx.x >> 6;

    // XCD-contiguous swizzle (gridDim.x = 2048, multiple of 8 -> bijective)
    const int nblk = gridDim.x;
    const int bid  = blockIdx.x;
    const int sw   = (bid & 7) * (nblk >> 3) + (bid >> 3);

    const int wid = sw * 4 + wv;        // 0..8191
    const int g0  = wid * 8;            // first of 8 consecutive chunks (same row: 8 | 1024)
    const int b   = g0 >> 10;
    const int c0  = g0 & 1023;

    const float4* dp = reinterpret_cast<const float4*>(data + (size_t)b * L_ + (size_t)c0 * 1024);

    // ---- issue first chunk's loads ASAP ----
    float4 A0 = dp[lane], A1 = dp[lane + 64], A2 = dp[lane + 128], A3 = dp[lane + 192];

    // ---- hoisted per-wave constants ----
    float4 tw[7];                        // s=2..8 taps (index via constexpr S only)
#pragma unroll
    for (int s = 2; s <= 8; ++s) {
        const int m = (1 << s) >> 2;
        tw[s - 2] = *reinterpret_cast<const float4*>(weights + ((1 << s) - 1) + ((lane & (m - 1)) << 2));
    }
    const float4 t9a = *reinterpret_cast<const float4*>(weights + 511 + (lane << 2));
    const float4 t9b = *reinterpret_cast<const float4*>(weights + 511 + 256 + (lane << 2));
    const float b2 = bias[1], b3 = bias[2], b4 = bias[3], b5 = bias[4], b6 = bias[5];
    const float b7 = bias[6], b8 = bias[7], b9 = bias[8], b10 = bias[9];

    float* orow = out + (size_t)b * OUT_LEN;

    // out[:, 0:1023) must be zero (harness poisons d_out); 64 waves do this
    if (c0 == 0) {
        for (int j = lane; j < 1023; j += 64) orow[j] = 0.0f;
    }

    for (int it = 0; it < 8; ++it) {
        // prefetch next chunk into B while computing A
        float4 B0, B1, B2, B3;
        if (it < 7) {
            const float4* np = dp + (it + 1) * 256;
            B0 = np[lane]; B1 = np[lane + 64]; B2 = np[lane + 128]; B3 = np[lane + 192];
        }

        const int c = c0 + it;

        scale_compute<2>(A0, A1, A2, A3, tw[0], b2, orow, c, lane);
        scale_compute<3>(A0, A1, A2, A3, tw[1], b3, orow, c, lane);
        scale_compute<4>(A0, A1, A2, A3, tw[2], b4, orow, c, lane);
        scale_compute<5>(A0, A1, A2, A3, tw[3], b5, orow, c, lane);
        scale_compute<6>(A0, A1, A2, A3, tw[4], b6, orow, c, lane);
        scale_compute<7>(A0, A1, A2, A3, tw[5], b7, orow, c, lane);
        scale_compute<8>(A0, A1, A2, A3, tw[6], b8, orow, c, lane);

        // s = 9 (w = 512): two segments per chunk
        {
            float p = dot4(A0, t9a.x, t9a.y, t9a.z, t9a.w) + dot4(A1, t9b.x, t9b.y, t9b.z, t9b.w);
            float q = dot4(A2, t9a.x, t9a.y, t9a.z, t9a.w) + dot4(A3, t9b.x, t9b.y, t9b.z, t9b.w);
            p = seg_reduce<64>(p);
            q = seg_reduce<64>(q);
            if (lane == 63) {
                orow[((L_ >> 9) - 1) + 2 * c    ] = p + b9;
                orow[((L_ >> 9) - 1) + 2 * c + 1] = q + b9;
            }
        }

        // s = 10 (w = 1024): one segment per chunk (taps reloaded, L1-resident)
        {
            const float* t = weights + 1023 + (lane << 2);
            const float4 u0 = *reinterpret_cast<const float4*>(t);
            const float4 u1 = *reinterpret_cast<const float4*>(t + 256);
            const float4 u2 = *reinterpret_cast<const float4*>(t + 512);
            const float4 u3 = *reinterpret_cast<const float4*>(t + 768);
            float p = dot4(A0, u0.x, u0.y, u0.z, u0.w);
            p      += dot4(A1, u1.x, u1.y, u1.z, u1.w);
            p      += dot4(A2, u2.x, u2.y, u2.z, u2.w);
            p      += dot4(A3, u3.x, u3.y, u3.z, u3.w);
            p = seg_reduce<64>(p);
            if (lane == 63) orow[((L_ >> 10) - 1) + c] = p + b10;
        }

        A0 = B0; A1 = B1; A2 = B2; A3 = B3;
    }
}

extern "C" void kernel_launch(void* const* d_in, const int* in_sizes, int n_in,
                              void* d_out, int out_size, void* d_ws, size_t ws_size,
                              hipStream_t stream) {
    const float* data    = (const float*)d_in[0];
    const float* weights = (const float*)d_in[1];
    const float* bias    = (const float*)d_in[2];
    float* out = (float*)d_out;

    dim3 grid(2048);                    // 8192 waves, 8 chunks each
    dim3 block(256);
    multiscale_conv<<<grid, block, 0, stream>>>(data, weights, bias, out);
}

// Round 6
// 91.429 us; speedup vs baseline: 1.1080x; 1.1080x over previous
//
#include <hip/hip_runtime.h>

static constexpr int B_ = 64;
static constexpr int L_ = 1 << 20;
static constexpr int OUT_LEN = 2 * (L_ >> 2) - 1; // 524287

__device__ __forceinline__ float dot4(const float4& v, float t0, float t1, float t2, float t3) {
    return fmaf(v.x, t0, fmaf(v.y, t1, fmaf(v.z, t2, v.w * t3)));
}

// v += dpp(v) on the VALU pipe. old=0 so masked-off rows contribute +0.
template<int CTRL, int RM>
__device__ __forceinline__ float dpp_add(float v) {
    int t = __builtin_amdgcn_update_dpp(0, __builtin_bit_cast(int, v), CTRL, RM, 0xF, true);
    return v + __builtin_bit_cast(float, t);
}

// Segmented sum over groups of M consecutive lanes; result in LAST lane of group.
template<int M>
__device__ __forceinline__ float seg_reduce(float v) {
    if constexpr (M >= 2)  v = dpp_add<0x111, 0xF>(v);  // row_shr:1
    if constexpr (M >= 4)  v = dpp_add<0x112, 0xF>(v);  // row_shr:2
    if constexpr (M >= 8)  v = dpp_add<0x114, 0xF>(v);  // row_shr:4
    if constexpr (M >= 16) v = dpp_add<0x118, 0xF>(v);  // row_shr:8
    if constexpr (M >= 32) v = dpp_add<0x142, 0xA>(v);  // row_bcast15
    if constexpr (M >= 64) v = dpp_add<0x143, 0xC>(v);  // row_bcast31
    return v;
}

template<int S>
__device__ __forceinline__ void do_scale(const float4& v0, const float4& v1,
                                         const float4& v2, const float4& v3,
                                         const float* __restrict__ weights,
                                         const float* __restrict__ bias,
                                         float* __restrict__ orow, int c, int lane) {
    constexpr int w = 1 << S;
    constexpr int m = w >> 2;
    const float* tp = weights + (w - 1) + ((lane & (m - 1)) << 2);
    const float t0 = tp[0], t1 = tp[1], t2 = tp[2], t3 = tp[3];
    float p0 = seg_reduce<m>(dot4(v0, t0, t1, t2, t3));
    float p1 = seg_reduce<m>(dot4(v1, t0, t1, t2, t3));
    float p2 = seg_reduce<m>(dot4(v2, t0, t1, t2, t3));
    float p3 = seg_reduce<m>(dot4(v3, t0, t1, t2, t3));
    if ((lane & (m - 1)) == (m - 1)) {
        constexpr int base = (L_ >> S) - 1;
        constexpr int sps  = 256 >> S;
        const int seg = c * (1024 >> S) + (lane >> (S - 2));
        const float bs = bias[S - 1];
        orow[base + seg          ] = p0 + bs;
        orow[base + seg +     sps] = p1 + bs;
        orow[base + seg + 2 * sps] = p2 + bs;
        orow[base + seg + 3 * sps] = p3 + bs;
    }
}

__device__ __forceinline__ void compute_chunk(const float4& v0, const float4& v1,
                                              const float4& v2, const float4& v3,
                                              const float* __restrict__ weights,
                                              const float* __restrict__ bias,
                                              float* __restrict__ orow, int c, int lane) {
    do_scale<2>(v0, v1, v2, v3, weights, bias, orow, c, lane);
    do_scale<3>(v0, v1, v2, v3, weights, bias, orow, c, lane);
    do_scale<4>(v0, v1, v2, v3, weights, bias, orow, c, lane);
    do_scale<5>(v0, v1, v2, v3, weights, bias, orow, c, lane);
    do_scale<6>(v0, v1, v2, v3, weights, bias, orow, c, lane);
    do_scale<7>(v0, v1, v2, v3, weights, bias, orow, c, lane);
    do_scale<8>(v0, v1, v2, v3, weights, bias, orow, c, lane);

    // s = 9 (w = 512): two segments per chunk
    {
        const float* ta = weights + 511 + (lane << 2);
        const float* tb = ta + 256;
        float p = dot4(v0, ta[0], ta[1], ta[2], ta[3]) + dot4(v1, tb[0], tb[1], tb[2], tb[3]);
        float q = dot4(v2, ta[0], ta[1], ta[2], ta[3]) + dot4(v3, tb[0], tb[1], tb[2], tb[3]);
        p = seg_reduce<64>(p);
        q = seg_reduce<64>(q);
        if (lane == 63) {
            const float bs = bias[8];
            orow[((L_ >> 9) - 1) + 2 * c    ] = p + bs;
            orow[((L_ >> 9) - 1) + 2 * c + 1] = q + bs;
        }
    }

    // s = 10 (w = 1024): one segment per chunk
    {
        const float* t = weights + 1023 + (lane << 2);
        float p = dot4(v0, t[0],   t[1],   t[2],   t[3]);
        p      += dot4(v1, t[256], t[257], t[258], t[259]);
        p      += dot4(v2, t[512], t[513], t[514], t[515]);
        p      += dot4(v3, t[768], t[769], t[770], t[771]);
        p = seg_reduce<64>(p);
        if (lane == 63) orow[((L_ >> 10) - 1) + c] = p + bias[9];
    }
}

__global__ __launch_bounds__(256) void multiscale_conv(
    const float* __restrict__ data,
    const float* __restrict__ weights,
    const float* __restrict__ bias,
    float* __restrict__ out)
{
    const int lane = threadIdx.x & 63;
    const int wv   = threadIdx.x >> 6;

    // XCD-contiguous swizzle (gridDim.x = 8192, multiple of 8 -> bijective)
    const int nblk = gridDim.x;
    const int bid  = blockIdx.x;
    const int sw   = (bid & 7) * (nblk >> 3) + (bid >> 3);

    const int wid = sw * 4 + wv;        // 0..32767
    const int g0  = wid * 2;            // 2 consecutive chunks, same row (2 | 1024)
    const int b   = g0 >> 10;
    const int c0  = g0 & 1023;

    const float4* dp = reinterpret_cast<const float4*>(data + (size_t)b * L_ + (size_t)c0 * 1024);

    // issue ALL 8 loads (8 KB) before any compute: 2x MLP, one latency exposure
    const float4 A0 = dp[lane      ], A1 = dp[lane +  64], A2 = dp[lane + 128], A3 = dp[lane + 192];
    const float4 C0 = dp[lane + 256], C1 = dp[lane + 320], C2 = dp[lane + 384], C3 = dp[lane + 448];

    float* orow = out + (size_t)b * OUT_LEN;

    // out[:, 0:1023) must be zero (harness poisons d_out)
    if (c0 == 0) {
        for (int j = lane; j < 1023; j += 64) orow[j] = 0.0f;
    }

    compute_chunk(A0, A1, A2, A3, weights, bias, orow, c0,     lane);
    compute_chunk(C0, C1, C2, C3, weights, bias, orow, c0 + 1, lane);
}

extern "C" void kernel_launch(void* const* d_in, const int* in_sizes, int n_in,
                              void* d_out, int out_size, void* d_ws, size_t ws_size,
                              hipStream_t stream) {
    const float* data    = (const float*)d_in[0];
    const float* weights = (const float*)d_in[1];
    const float* bias    = (const float*)d_in[2];
    float* out = (float*)d_out;

    dim3 grid(8192);                    // 32768 waves, 2 chunks each
    dim3 block(256);
    multiscale_conv<<<grid, block, 0, stream>>>(data, weights, bias, out);
}